// Round 1
// baseline (1541.248 us; speedup 1.0000x reference)
//
#include <hip/hip_runtime.h>

#define N_NODES 100000
#define N_EDGES 1600000
#define NB1 391  // ceil(N_NODES/256)

// ---------------- scores = x @ W_base + b_base ----------------
// 10 threads per row, each owns 4 output columns (float4). 32 rows/block.
__global__ __launch_bounds__(320) void scores_kernel(
    const float* __restrict__ x, const float* __restrict__ Wb,
    const float* __restrict__ bb, float* __restrict__ scores)
{
    int tid = threadIdx.x;
    int c4  = tid % 10;
    int r   = blockIdx.x * 32 + tid / 10;
    const float4* x4 = (const float4*)x + (size_t)r * 125;  // 500 floats/row
    const float4* W4 = (const float4*)Wb;                   // [500][10] float4
    float4 acc = make_float4(0.f, 0.f, 0.f, 0.f);
    for (int k4 = 0; k4 < 125; ++k4) {
        float4 xv = x4[k4];
        int kb = k4 * 40 + c4;
        float4 w0 = W4[kb];
        float4 w1 = W4[kb + 10];
        float4 w2 = W4[kb + 20];
        float4 w3 = W4[kb + 30];
        acc.x = fmaf(xv.x, w0.x, acc.x); acc.y = fmaf(xv.x, w0.y, acc.y);
        acc.z = fmaf(xv.x, w0.z, acc.z); acc.w = fmaf(xv.x, w0.w, acc.w);
        acc.x = fmaf(xv.y, w1.x, acc.x); acc.y = fmaf(xv.y, w1.y, acc.y);
        acc.z = fmaf(xv.y, w1.z, acc.z); acc.w = fmaf(xv.y, w1.w, acc.w);
        acc.x = fmaf(xv.z, w2.x, acc.x); acc.y = fmaf(xv.z, w2.y, acc.y);
        acc.z = fmaf(xv.z, w2.z, acc.z); acc.w = fmaf(xv.z, w2.w, acc.w);
        acc.x = fmaf(xv.w, w3.x, acc.x); acc.y = fmaf(xv.w, w3.y, acc.y);
        acc.z = fmaf(xv.w, w3.z, acc.z); acc.w = fmaf(xv.w, w3.w, acc.w);
    }
    float4 b4 = ((const float4*)bb)[c4];
    acc.x += b4.x; acc.y += b4.y; acc.z += b4.z; acc.w += b4.w;
    ((float4*)scores)[(size_t)blockIdx.x * 320 + tid] = acc;
}

// ---------------- softmax + MLP(40->64 relu ->40) ----------------
// one wave (64 lanes) per row; 4 rows per 256-thread block
__global__ __launch_bounds__(256) void mlp_kernel(
    const float* __restrict__ scores,
    const float* __restrict__ W1, const float* __restrict__ b1,
    const float* __restrict__ W2, const float* __restrict__ b2,
    float* __restrict__ h0)
{
    int lane = threadIdx.x & 63;
    int row  = blockIdx.x * 4 + (threadIdx.x >> 6);
    float s = (lane < 40) ? scores[(size_t)row * 40 + lane] : -1e30f;
    float m = s;
    #pragma unroll
    for (int off = 32; off; off >>= 1) m = fmaxf(m, __shfl_xor(m, off));
    float e = (lane < 40) ? __expf(s - m) : 0.f;
    float sum = e;
    #pragma unroll
    for (int off = 32; off; off >>= 1) sum += __shfl_xor(sum, off);
    float p = e / sum;  // softmax prob (lanes >=40 hold 0)

    // h1[j] = relu(b1[j] + sum_i p[i]*W1[i][j]), j = lane (64 wide)
    float acc1 = b1[lane];
    #pragma unroll
    for (int i = 0; i < 40; ++i)
        acc1 = fmaf(__shfl(p, i), W1[i * 64 + lane], acc1);
    float h1 = fmaxf(acc1, 0.f);

    // h2[c] = b2[c] + sum_j h1[j]*W2[j][c], c = lane < 40
    int cc = lane < 40 ? lane : 39;
    float acc2 = b2[cc];
    #pragma unroll
    for (int j = 0; j < 64; ++j)
        acc2 = fmaf(__shfl(h1, j), W2[j * 40 + cc], acc2);
    if (lane < 40) h0[(size_t)row * 40 + lane] = acc2;
}

// ---------------- degree count ----------------
__global__ __launch_bounds__(256) void deg_kernel(
    const int* __restrict__ src, const int* __restrict__ dst,
    int* __restrict__ deg_out, int* __restrict__ deg_in)
{
    int e = blockIdx.x * 256 + threadIdx.x;
    if (e < N_EDGES) {
        atomicAdd(&deg_out[src[e]], 1);
        atomicAdd(&deg_in[dst[e]], 1);
    }
}

__global__ __launch_bounds__(256) void inv_kernel(
    const int* __restrict__ deg_out, const int* __restrict__ deg_in,
    float* __restrict__ inv_out, float* __restrict__ inv_in)
{
    int i = blockIdx.x * 256 + threadIdx.x;
    if (i < N_NODES) {
        int a = deg_out[i], b = deg_in[i];
        inv_out[i] = (a > 0) ? rsqrtf((float)a) : 0.f;
        inv_in[i]  = (b > 0) ? rsqrtf((float)b) : 0.f;
    }
}

// ---------------- exclusive scan of deg_in -> row_start ----------------
__global__ __launch_bounds__(256) void scan1_kernel(
    const int* __restrict__ deg_in, int* __restrict__ row_start, int* __restrict__ bsum)
{
    __shared__ int tmp[256];
    int t = threadIdx.x;
    int i = blockIdx.x * 256 + t;
    int v = (i < N_NODES) ? deg_in[i] : 0;
    tmp[t] = v;
    __syncthreads();
    #pragma unroll
    for (int off = 1; off < 256; off <<= 1) {
        int add = (t >= off) ? tmp[t - off] : 0;
        __syncthreads();
        tmp[t] += add;
        __syncthreads();
    }
    if (i < N_NODES) row_start[i] = tmp[t] - v;
    if (t == 255) bsum[blockIdx.x] = tmp[t];
}

__global__ __launch_bounds__(512) void scan2_kernel(int* __restrict__ bsum)
{
    __shared__ int tmp[512];
    int t = threadIdx.x;
    int v = (t < NB1) ? bsum[t] : 0;
    tmp[t] = v;
    __syncthreads();
    #pragma unroll
    for (int off = 1; off < 512; off <<= 1) {
        int add = (t >= off) ? tmp[t - off] : 0;
        __syncthreads();
        tmp[t] += add;
        __syncthreads();
    }
    if (t < NB1) bsum[t] = tmp[t] - v;  // exclusive
}

__global__ __launch_bounds__(256) void scan3_kernel(
    int* __restrict__ row_start, const int* __restrict__ bsum)
{
    int i = blockIdx.x * 256 + threadIdx.x;
    if (i < N_NODES) row_start[i] += bsum[i >> 8];
}

// ---------------- CSR placement + per-edge weight ----------------
__global__ __launch_bounds__(256) void place_kernel(
    const int* __restrict__ src, const int* __restrict__ dst,
    const float* __restrict__ inv_out, const float* __restrict__ inv_in,
    const int* __restrict__ row_start, int* __restrict__ cursor,
    int* __restrict__ csr_src, float* __restrict__ csr_w)
{
    int e = blockIdx.x * 256 + threadIdx.x;
    if (e < N_EDGES) {
        int s = src[e], d = dst[e];
        int off = atomicAdd(&cursor[d], 1);
        int idx = row_start[d] + off;
        csr_src[idx] = s;
        csr_w[idx] = 0.9f * inv_out[s] * inv_in[d];  // (1-alpha) folded in
    }
}

// ---------------- one APPNP hop, pull-based, no atomics ----------------
// thread = (dst node, channel quad); h_new = alpha*h0 + sum_e w*h_cur[src]
__global__ __launch_bounds__(256) void hop_kernel(
    const float4* __restrict__ hcur, const float4* __restrict__ h0,
    const int* __restrict__ row_start, const int* __restrict__ deg,
    const int* __restrict__ csr_src, const float* __restrict__ csr_w,
    float4* __restrict__ hnew)
{
    int gid = blockIdx.x * 256 + threadIdx.x;
    if (gid >= 10 * N_NODES) return;
    int d = gid / 10;
    int q = gid - d * 10;
    float4 hv0 = h0[gid];
    float4 acc = make_float4(0.1f * hv0.x, 0.1f * hv0.y, 0.1f * hv0.z, 0.1f * hv0.w);
    int beg = row_start[d];
    int end = beg + deg[d];
    for (int j = beg; j < end; ++j) {
        int s   = csr_src[j];   // broadcast across the 10 quad-threads of d
        float w = csr_w[j];
        float4 hv = hcur[s * 10 + q];
        acc.x = fmaf(w, hv.x, acc.x);
        acc.y = fmaf(w, hv.y, acc.y);
        acc.z = fmaf(w, hv.z, acc.z);
        acc.w = fmaf(w, hv.w, acc.w);
    }
    hnew[gid] = acc;
}

extern "C" void kernel_launch(void* const* d_in, const int* in_sizes, int n_in,
                              void* d_out, int out_size, void* d_ws, size_t ws_size,
                              hipStream_t stream) {
    const float* x  = (const float*)d_in[0];
    const int*   ei = (const int*)d_in[1];
    const int*   src = ei;
    const int*   dst = ei + N_EDGES;
    const float* Wb = (const float*)d_in[2];
    const float* bb = (const float*)d_in[3];
    const float* W1 = (const float*)d_in[4];
    const float* b1 = (const float*)d_in[5];
    const float* W2 = (const float*)d_in[6];
    const float* b2 = (const float*)d_in[7];

    float* out_adj    = (float*)d_out;              // [N,40] adjust_scores
    float* out_scores = (float*)d_out + 4000000;    // [N,40] scores

    // workspace layout (all 16B-aligned chunks)
    float* h0      = (float*)d_ws;                  // 4,000,000 f
    float* hA      = h0 + 4000000;                  // 4,000,000 f
    int* deg_out   = (int*)(hA + 4000000);          // N
    int* deg_in    = deg_out + N_NODES;             // N
    int* cursor    = deg_in + N_NODES;              // N
    float* inv_out = (float*)(cursor + N_NODES);    // N
    float* inv_in  = inv_out + N_NODES;             // N
    int* row_start = (int*)(inv_in + N_NODES);      // N
    int* bsum      = row_start + N_NODES;           // 1024
    int* csr_src   = bsum + 1024;                   // E
    float* csr_w   = (float*)(csr_src + N_EDGES);   // E

    // zero deg_out, deg_in, cursor (contiguous)
    hipMemsetAsync(deg_out, 0, 3 * N_NODES * sizeof(int), stream);

    deg_kernel<<<N_EDGES / 256, 256, 0, stream>>>(src, dst, deg_out, deg_in);
    inv_kernel<<<NB1, 256, 0, stream>>>(deg_out, deg_in, inv_out, inv_in);
    scan1_kernel<<<NB1, 256, 0, stream>>>(deg_in, row_start, bsum);
    scan2_kernel<<<1, 512, 0, stream>>>(bsum);
    scan3_kernel<<<NB1, 256, 0, stream>>>(row_start, bsum);
    place_kernel<<<N_EDGES / 256, 256, 0, stream>>>(src, dst, inv_out, inv_in,
                                                    row_start, cursor, csr_src, csr_w);

    scores_kernel<<<N_NODES / 32, 320, 0, stream>>>(x, Wb, bb, out_scores);
    mlp_kernel<<<N_NODES / 4, 256, 0, stream>>>(out_scores, W1, b1, W2, b2, h0);

    // 10 hops, ping-pong between hA and the d_out adjust region (hop 9 lands on d_out)
    const float* cur = h0;
    for (int k = 0; k < 10; ++k) {
        float* dstbuf = (k & 1) ? out_adj : hA;
        if (k == 9) dstbuf = out_adj;
        hop_kernel<<<(10 * N_NODES + 255) / 256, 256, 0, stream>>>(
            (const float4*)cur, (const float4*)h0, row_start, deg_in,
            csr_src, csr_w, (float4*)dstbuf);
        cur = dstbuf;
    }
}

// Round 2
// 1339.514 us; speedup vs baseline: 1.1506x; 1.1506x over previous
//
#include <hip/hip_runtime.h>

#define N_NODES 100000
#define N_EDGES 1600000
#define NB1 391  // ceil(N_NODES/256)

// ---------------- scores = x @ W_base + b_base ----------------
// Register-tiled GEMM: block = 320 threads = 32 rowgroups x 10 colgroups.
// Each thread computes 4 rows x 4 cols. Block covers 128 rows x 40 cols.
// W staged through LDS in 5 chunks of K=100 (16 KB each).
#define FMA4(ACC, XS, W) \
    ACC.x = fmaf(XS, W.x, ACC.x); ACC.y = fmaf(XS, W.y, ACC.y); \
    ACC.z = fmaf(XS, W.z, ACC.z); ACC.w = fmaf(XS, W.w, ACC.w);

__global__ __launch_bounds__(320) void scores_kernel(
    const float4* __restrict__ x4, const float4* __restrict__ W4,
    const float* __restrict__ bb, float4* __restrict__ s4)
{
    __shared__ float4 Wl[1000];  // 100 k-steps x 10 col-quads = 16 KB
    int t  = threadIdx.x;
    int c  = t % 10;             // col quad (4 cols)
    int rg = t / 10;             // row group
    int r0 = blockIdx.x * 128 + rg * 4;
    int r0c = min(r0, N_NODES - 4);  // clamp for loads; stores guarded by r0

    float4 acc0 = {0,0,0,0}, acc1 = {0,0,0,0}, acc2 = {0,0,0,0}, acc3 = {0,0,0,0};

    for (int ch = 0; ch < 5; ++ch) {
        if (ch) __syncthreads();
        for (int i = t; i < 1000; i += 320)
            Wl[i] = W4[ch * 1000 + i];
        __syncthreads();
        const float4* xp = x4 + (size_t)r0c * 125 + ch * 25;
        #pragma unroll 5
        for (int k4 = 0; k4 < 25; ++k4) {
            float4 xv0 = xp[k4];
            float4 xv1 = xp[k4 + 125];
            float4 xv2 = xp[k4 + 250];
            float4 xv3 = xp[k4 + 375];
            const float4* wp = &Wl[k4 * 40 + c];
            float4 w0 = wp[0], w1 = wp[10], w2 = wp[20], w3 = wp[30];
            FMA4(acc0, xv0.x, w0) FMA4(acc0, xv0.y, w1) FMA4(acc0, xv0.z, w2) FMA4(acc0, xv0.w, w3)
            FMA4(acc1, xv1.x, w0) FMA4(acc1, xv1.y, w1) FMA4(acc1, xv1.z, w2) FMA4(acc1, xv1.w, w3)
            FMA4(acc2, xv2.x, w0) FMA4(acc2, xv2.y, w1) FMA4(acc2, xv2.z, w2) FMA4(acc2, xv2.w, w3)
            FMA4(acc3, xv3.x, w0) FMA4(acc3, xv3.y, w1) FMA4(acc3, xv3.z, w2) FMA4(acc3, xv3.w, w3)
        }
    }
    float4 b4 = ((const float4*)bb)[c];
    acc0.x += b4.x; acc0.y += b4.y; acc0.z += b4.z; acc0.w += b4.w;
    acc1.x += b4.x; acc1.y += b4.y; acc1.z += b4.z; acc1.w += b4.w;
    acc2.x += b4.x; acc2.y += b4.y; acc2.z += b4.z; acc2.w += b4.w;
    acc3.x += b4.x; acc3.y += b4.y; acc3.z += b4.z; acc3.w += b4.w;
    if (r0 + 0 < N_NODES) s4[(size_t)(r0 + 0) * 10 + c] = acc0;
    if (r0 + 1 < N_NODES) s4[(size_t)(r0 + 1) * 10 + c] = acc1;
    if (r0 + 2 < N_NODES) s4[(size_t)(r0 + 2) * 10 + c] = acc2;
    if (r0 + 3 < N_NODES) s4[(size_t)(r0 + 3) * 10 + c] = acc3;
}

// ---------------- softmax + MLP(40->64 relu ->40) ----------------
// one wave (64 lanes) per row; 4 rows per 256-thread block
__global__ __launch_bounds__(256) void mlp_kernel(
    const float* __restrict__ scores,
    const float* __restrict__ W1, const float* __restrict__ b1,
    const float* __restrict__ W2, const float* __restrict__ b2,
    float* __restrict__ h0)
{
    int lane = threadIdx.x & 63;
    int row  = blockIdx.x * 4 + (threadIdx.x >> 6);
    float s = (lane < 40) ? scores[(size_t)row * 40 + lane] : -1e30f;
    float m = s;
    #pragma unroll
    for (int off = 32; off; off >>= 1) m = fmaxf(m, __shfl_xor(m, off));
    float e = (lane < 40) ? __expf(s - m) : 0.f;
    float sum = e;
    #pragma unroll
    for (int off = 32; off; off >>= 1) sum += __shfl_xor(sum, off);
    float p = e / sum;  // softmax prob (lanes >=40 hold 0)

    // h1[j] = relu(b1[j] + sum_i p[i]*W1[i][j]), j = lane (64 wide)
    float acc1 = b1[lane];
    #pragma unroll
    for (int i = 0; i < 40; ++i)
        acc1 = fmaf(__shfl(p, i), W1[i * 64 + lane], acc1);
    float h1 = fmaxf(acc1, 0.f);

    // h2[c] = b2[c] + sum_j h1[j]*W2[j][c], c = lane < 40
    int cc = lane < 40 ? lane : 39;
    float acc2 = b2[cc];
    #pragma unroll
    for (int j = 0; j < 64; ++j)
        acc2 = fmaf(__shfl(h1, j), W2[j * 40 + cc], acc2);
    if (lane < 40) h0[(size_t)row * 40 + lane] = acc2;
}

// ---------------- degree count ----------------
__global__ __launch_bounds__(256) void deg_kernel(
    const int* __restrict__ src, const int* __restrict__ dst,
    int* __restrict__ deg_out, int* __restrict__ deg_in)
{
    int e = blockIdx.x * 256 + threadIdx.x;
    if (e < N_EDGES) {
        atomicAdd(&deg_out[src[e]], 1);
        atomicAdd(&deg_in[dst[e]], 1);
    }
}

__global__ __launch_bounds__(256) void inv_kernel(
    const int* __restrict__ deg_out, const int* __restrict__ deg_in,
    float* __restrict__ inv_out, float* __restrict__ inv_in)
{
    int i = blockIdx.x * 256 + threadIdx.x;
    if (i < N_NODES) {
        int a = deg_out[i], b = deg_in[i];
        inv_out[i] = (a > 0) ? rsqrtf((float)a) : 0.f;
        inv_in[i]  = (b > 0) ? rsqrtf((float)b) : 0.f;
    }
}

// ---------------- exclusive scan of deg_in -> row_start ----------------
__global__ __launch_bounds__(256) void scan1_kernel(
    const int* __restrict__ deg_in, int* __restrict__ row_start, int* __restrict__ bsum)
{
    __shared__ int tmp[256];
    int t = threadIdx.x;
    int i = blockIdx.x * 256 + t;
    int v = (i < N_NODES) ? deg_in[i] : 0;
    tmp[t] = v;
    __syncthreads();
    #pragma unroll
    for (int off = 1; off < 256; off <<= 1) {
        int add = (t >= off) ? tmp[t - off] : 0;
        __syncthreads();
        tmp[t] += add;
        __syncthreads();
    }
    if (i < N_NODES) row_start[i] = tmp[t] - v;
    if (t == 255) bsum[blockIdx.x] = tmp[t];
}

__global__ __launch_bounds__(512) void scan2_kernel(int* __restrict__ bsum)
{
    __shared__ int tmp[512];
    int t = threadIdx.x;
    int v = (t < NB1) ? bsum[t] : 0;
    tmp[t] = v;
    __syncthreads();
    #pragma unroll
    for (int off = 1; off < 512; off <<= 1) {
        int add = (t >= off) ? tmp[t - off] : 0;
        __syncthreads();
        tmp[t] += add;
        __syncthreads();
    }
    if (t < NB1) bsum[t] = tmp[t] - v;  // exclusive
}

__global__ __launch_bounds__(256) void scan3_kernel(
    int* __restrict__ row_start, const int* __restrict__ bsum)
{
    int i = blockIdx.x * 256 + threadIdx.x;
    if (i < N_NODES) row_start[i] += bsum[i >> 8];
    if (i == 0) row_start[N_NODES] = N_EDGES;  // sentinel: row_start[d+1] valid
}

// ---------------- CSR placement + per-edge weight ----------------
__global__ __launch_bounds__(256) void place_kernel(
    const int* __restrict__ src, const int* __restrict__ dst,
    const float* __restrict__ inv_out, const float* __restrict__ inv_in,
    const int* __restrict__ row_start, int* __restrict__ cursor,
    int* __restrict__ csr_src, float* __restrict__ csr_w)
{
    int e = blockIdx.x * 256 + threadIdx.x;
    if (e < N_EDGES) {
        int s = src[e], d = dst[e];
        int off = atomicAdd(&cursor[d], 1);
        int idx = row_start[d] + off;
        csr_src[idx] = s;
        csr_w[idx] = 0.9f * inv_out[s] * inv_in[d];  // (1-alpha) folded in
    }
}

// ---------------- one APPNP hop, pull-based, no atomics ----------------
// thread = (dst node, channel quad); h_new = alpha*h0 + sum_e w*h_cur[src]
__global__ __launch_bounds__(256) void hop_kernel(
    const float4* __restrict__ hcur, const float4* __restrict__ h0,
    const int* __restrict__ row_start,
    const int* __restrict__ csr_src, const float* __restrict__ csr_w,
    float4* __restrict__ hnew)
{
    int gid = blockIdx.x * 256 + threadIdx.x;
    if (gid >= 10 * N_NODES) return;
    int d = gid / 10;
    int q = gid - d * 10;
    float4 hv0 = h0[gid];
    float4 acc = make_float4(0.1f * hv0.x, 0.1f * hv0.y, 0.1f * hv0.z, 0.1f * hv0.w);
    int beg = row_start[d];
    int end = row_start[d + 1];
    for (int j = beg; j < end; ++j) {
        int s   = csr_src[j];   // broadcast across the 10 quad-threads of d
        float w = csr_w[j];
        float4 hv = hcur[s * 10 + q];
        acc.x = fmaf(w, hv.x, acc.x);
        acc.y = fmaf(w, hv.y, acc.y);
        acc.z = fmaf(w, hv.z, acc.z);
        acc.w = fmaf(w, hv.w, acc.w);
    }
    hnew[gid] = acc;
}

extern "C" void kernel_launch(void* const* d_in, const int* in_sizes, int n_in,
                              void* d_out, int out_size, void* d_ws, size_t ws_size,
                              hipStream_t stream) {
    const float* x  = (const float*)d_in[0];
    const int*   ei = (const int*)d_in[1];
    const int*   src = ei;
    const int*   dst = ei + N_EDGES;
    const float* Wb = (const float*)d_in[2];
    const float* bb = (const float*)d_in[3];
    const float* W1 = (const float*)d_in[4];
    const float* b1 = (const float*)d_in[5];
    const float* W2 = (const float*)d_in[6];
    const float* b2 = (const float*)d_in[7];

    float* out_adj    = (float*)d_out;              // [N,40] adjust_scores
    float* out_scores = (float*)d_out + 4000000;    // [N,40] scores

    // workspace layout (all 16B-aligned chunks)
    float* h0      = (float*)d_ws;                  // 4,000,000 f
    float* hA      = h0 + 4000000;                  // 4,000,000 f
    int* deg_out   = (int*)(hA + 4000000);          // N
    int* deg_in    = deg_out + N_NODES;             // N
    int* cursor    = deg_in + N_NODES;              // N
    float* inv_out = (float*)(cursor + N_NODES);    // N
    float* inv_in  = inv_out + N_NODES;             // N
    int* row_start = (int*)(inv_in + N_NODES);      // N+1
    int* bsum      = row_start + N_NODES + 16;      // 1024
    int* csr_src   = bsum + 1024;                   // E
    float* csr_w   = (float*)(csr_src + N_EDGES);   // E

    // zero deg_out, deg_in, cursor (contiguous)
    hipMemsetAsync(deg_out, 0, 3 * N_NODES * sizeof(int), stream);

    deg_kernel<<<N_EDGES / 256, 256, 0, stream>>>(src, dst, deg_out, deg_in);
    inv_kernel<<<NB1, 256, 0, stream>>>(deg_out, deg_in, inv_out, inv_in);
    scan1_kernel<<<NB1, 256, 0, stream>>>(deg_in, row_start, bsum);
    scan2_kernel<<<1, 512, 0, stream>>>(bsum);
    scan3_kernel<<<NB1, 256, 0, stream>>>(row_start, bsum);
    place_kernel<<<N_EDGES / 256, 256, 0, stream>>>(src, dst, inv_out, inv_in,
                                                    row_start, cursor, csr_src, csr_w);

    scores_kernel<<<782, 320, 0, stream>>>(
        (const float4*)x, (const float4*)Wb, bb, (float4*)out_scores);
    mlp_kernel<<<N_NODES / 4, 256, 0, stream>>>(out_scores, W1, b1, W2, b2, h0);

    // 10 hops, ping-pong between hA and the d_out adjust region (hop 9 lands on d_out)
    const float* cur = h0;
    for (int k = 0; k < 10; ++k) {
        float* dstbuf = (k & 1) ? out_adj : hA;
        if (k == 9) dstbuf = out_adj;
        hop_kernel<<<(10 * N_NODES + 255) / 256, 256, 0, stream>>>(
            (const float4*)cur, (const float4*)h0, row_start,
            csr_src, csr_w, (float4*)dstbuf);
        cur = dstbuf;
    }
}

// Round 3
// 1207.036 us; speedup vs baseline: 1.2769x; 1.1098x over previous
//
#include <hip/hip_runtime.h>

#define N_NODES 100000
#define N_EDGES 1600000
#define NB1 391  // ceil(N_NODES/256)

typedef __attribute__((ext_vector_type(8))) short short8;
typedef __attribute__((ext_vector_type(4))) float floatx4;

__device__ inline short bf16_rne(float f) {
    union { float f; unsigned u; } v; v.f = f;
    unsigned r = v.u + 0x7FFF + ((v.u >> 16) & 1);
    return (short)(r >> 16);
}

// ---------------- W^T prep: WT[48][512] bf16, zero-padded ----------------
__global__ __launch_bounds__(256) void wt_kernel(
    const float* __restrict__ Wb, short* __restrict__ WT)
{
    int i = blockIdx.x * 256 + threadIdx.x;
    if (i < 48 * 512) {
        int m = i >> 9, k = i & 511;
        float v = (m < 40 && k < 500) ? Wb[k * 40 + m] : 0.f;
        WT[i] = bf16_rne(v);
    }
}

// ---------------- scores = x @ W_base + b_base via MFMA ----------------
// D = W^T (A, 48x512 bf16, L1-hot) · x^T (B, built per-lane from 8 consecutive
// floats of one x row). One wave = 16 nodes, all 40 (padded 48) cols.
// C/D: col(lane&15)=node, row(quad*4+reg)=score col  [m89/m91 layout]
__global__ __launch_bounds__(256) void scores_kernel(
    const float* __restrict__ x, const short8* __restrict__ WT8,
    const float* __restrict__ bb, float* __restrict__ scores)
{
    int wave = threadIdx.x >> 6;
    int lane = threadIdx.x & 63;
    int n0 = (blockIdx.x * 4 + wave) * 16;
    if (n0 >= N_NODES) return;
    int n = n0 + (lane & 15);
    int quad = lane >> 4;
    int m = lane & 15;
    const float* xrow = x + (size_t)n * 500 + quad * 8;

    floatx4 acc0 = {0,0,0,0}, acc1 = {0,0,0,0}, acc2 = {0,0,0,0};

    #pragma unroll 5
    for (int ks = 0; ks < 15; ++ks) {
        int k0 = ks * 32;
        float4 xa = *(const float4*)(xrow + k0);
        float4 xb = *(const float4*)(xrow + k0 + 4);
        short8 bf;
        bf[0] = bf16_rne(xa.x); bf[1] = bf16_rne(xa.y);
        bf[2] = bf16_rne(xa.z); bf[3] = bf16_rne(xa.w);
        bf[4] = bf16_rne(xb.x); bf[5] = bf16_rne(xb.y);
        bf[6] = bf16_rne(xb.z); bf[7] = bf16_rne(xb.w);
        int widx = (k0 >> 3) + quad;
        short8 a0 = WT8[(size_t)(0  + m) * 64 + widx];
        short8 a1 = WT8[(size_t)(16 + m) * 64 + widx];
        short8 a2 = WT8[(size_t)(32 + m) * 64 + widx];
        acc0 = __builtin_amdgcn_mfma_f32_16x16x32_bf16(a0, bf, acc0, 0, 0, 0);
        acc1 = __builtin_amdgcn_mfma_f32_16x16x32_bf16(a1, bf, acc1, 0, 0, 0);
        acc2 = __builtin_amdgcn_mfma_f32_16x16x32_bf16(a2, bf, acc2, 0, 0, 0);
    }
    {   // K tail: k0=480, k = 480+quad*8+j. A is zero for k>=500, so B only
        // needs to avoid OOB reads; garbage contributions are multiplied by 0.
        int kbase = 480 + quad * 8;
        float4 xa = {0,0,0,0}, xb = {0,0,0,0};
        if (kbase + 8 <= 500) { xa = *(const float4*)(xrow + 480); xb = *(const float4*)(xrow + 484); }
        else if (kbase < 500) { xa = *(const float4*)(xrow + 480); }
        short8 bf;
        bf[0] = bf16_rne(xa.x); bf[1] = bf16_rne(xa.y);
        bf[2] = bf16_rne(xa.z); bf[3] = bf16_rne(xa.w);
        bf[4] = bf16_rne(xb.x); bf[5] = bf16_rne(xb.y);
        bf[6] = bf16_rne(xb.z); bf[7] = bf16_rne(xb.w);
        int widx = 60 + quad;
        short8 a0 = WT8[(size_t)(0  + m) * 64 + widx];
        short8 a1 = WT8[(size_t)(16 + m) * 64 + widx];
        short8 a2 = WT8[(size_t)(32 + m) * 64 + widx];
        acc0 = __builtin_amdgcn_mfma_f32_16x16x32_bf16(a0, bf, acc0, 0, 0, 0);
        acc1 = __builtin_amdgcn_mfma_f32_16x16x32_bf16(a1, bf, acc1, 0, 0, 0);
        acc2 = __builtin_amdgcn_mfma_f32_16x16x32_bf16(a2, bf, acc2, 0, 0, 0);
    }

    float* srow = scores + (size_t)n * 40;
    int mb = quad * 4;
    float4 b4 = *(const float4*)(bb + mb);
    *(float4*)(srow + mb) = make_float4(acc0[0] + b4.x, acc0[1] + b4.y,
                                        acc0[2] + b4.z, acc0[3] + b4.w);
    mb = 16 + quad * 4;
    b4 = *(const float4*)(bb + mb);
    *(float4*)(srow + mb) = make_float4(acc1[0] + b4.x, acc1[1] + b4.y,
                                        acc1[2] + b4.z, acc1[3] + b4.w);
    mb = 32 + quad * 4;
    if (mb < 40) {
        b4 = *(const float4*)(bb + mb);
        *(float4*)(srow + mb) = make_float4(acc2[0] + b4.x, acc2[1] + b4.y,
                                            acc2[2] + b4.z, acc2[3] + b4.w);
    }
}

// ---------------- softmax + MLP(40->64 relu ->40) ----------------
__global__ __launch_bounds__(256) void mlp_kernel(
    const float* __restrict__ scores,
    const float* __restrict__ W1, const float* __restrict__ b1,
    const float* __restrict__ W2, const float* __restrict__ b2,
    float* __restrict__ h0)
{
    int lane = threadIdx.x & 63;
    int row  = blockIdx.x * 4 + (threadIdx.x >> 6);
    float s = (lane < 40) ? scores[(size_t)row * 40 + lane] : -1e30f;
    float m = s;
    #pragma unroll
    for (int off = 32; off; off >>= 1) m = fmaxf(m, __shfl_xor(m, off));
    float e = (lane < 40) ? __expf(s - m) : 0.f;
    float sum = e;
    #pragma unroll
    for (int off = 32; off; off >>= 1) sum += __shfl_xor(sum, off);
    float p = e / sum;

    float acc1 = b1[lane];
    #pragma unroll
    for (int i = 0; i < 40; ++i)
        acc1 = fmaf(__shfl(p, i), W1[i * 64 + lane], acc1);
    float h1 = fmaxf(acc1, 0.f);

    int cc = lane < 40 ? lane : 39;
    float acc2 = b2[cc];
    #pragma unroll
    for (int j = 0; j < 64; ++j)
        acc2 = fmaf(__shfl(h1, j), W2[j * 40 + cc], acc2);
    if (lane < 40) h0[(size_t)row * 40 + lane] = acc2;
}

// ---------------- degree count ----------------
__global__ __launch_bounds__(256) void deg_kernel(
    const int* __restrict__ src, const int* __restrict__ dst,
    int* __restrict__ deg_out, int* __restrict__ deg_in)
{
    int e = blockIdx.x * 256 + threadIdx.x;
    if (e < N_EDGES) {
        atomicAdd(&deg_out[src[e]], 1);
        atomicAdd(&deg_in[dst[e]], 1);
    }
}

__global__ __launch_bounds__(256) void inv_kernel(
    const int* __restrict__ deg_out, const int* __restrict__ deg_in,
    float* __restrict__ inv_out, float* __restrict__ inv_in)
{
    int i = blockIdx.x * 256 + threadIdx.x;
    if (i < N_NODES) {
        int a = deg_out[i], b = deg_in[i];
        inv_out[i] = (a > 0) ? rsqrtf((float)a) : 0.f;
        inv_in[i]  = (b > 0) ? rsqrtf((float)b) : 0.f;
    }
}

// ---------------- exclusive scan of deg_in -> row_start ----------------
__global__ __launch_bounds__(256) void scan1_kernel(
    const int* __restrict__ deg_in, int* __restrict__ row_start, int* __restrict__ bsum)
{
    __shared__ int tmp[256];
    int t = threadIdx.x;
    int i = blockIdx.x * 256 + t;
    int v = (i < N_NODES) ? deg_in[i] : 0;
    tmp[t] = v;
    __syncthreads();
    #pragma unroll
    for (int off = 1; off < 256; off <<= 1) {
        int add = (t >= off) ? tmp[t - off] : 0;
        __syncthreads();
        tmp[t] += add;
        __syncthreads();
    }
    if (i < N_NODES) row_start[i] = tmp[t] - v;
    if (t == 255) bsum[blockIdx.x] = tmp[t];
}

__global__ __launch_bounds__(512) void scan2_kernel(int* __restrict__ bsum)
{
    __shared__ int tmp[512];
    int t = threadIdx.x;
    int v = (t < NB1) ? bsum[t] : 0;
    tmp[t] = v;
    __syncthreads();
    #pragma unroll
    for (int off = 1; off < 512; off <<= 1) {
        int add = (t >= off) ? tmp[t - off] : 0;
        __syncthreads();
        tmp[t] += add;
        __syncthreads();
    }
    if (t < NB1) bsum[t] = tmp[t] - v;  // exclusive
}

__global__ __launch_bounds__(256) void scan3_kernel(
    int* __restrict__ row_start, const int* __restrict__ bsum)
{
    int i = blockIdx.x * 256 + threadIdx.x;
    if (i < N_NODES) row_start[i] += bsum[i >> 8];
    if (i == 0) row_start[N_NODES] = N_EDGES;  // sentinel
}

// ---------------- CSR placement + per-edge weight ----------------
__global__ __launch_bounds__(256) void place_kernel(
    const int* __restrict__ src, const int* __restrict__ dst,
    const float* __restrict__ inv_out, const float* __restrict__ inv_in,
    const int* __restrict__ row_start, int* __restrict__ cursor,
    int* __restrict__ csr_src10, float* __restrict__ csr_w)
{
    int e = blockIdx.x * 256 + threadIdx.x;
    if (e < N_EDGES) {
        int s = src[e], d = dst[e];
        int off = atomicAdd(&cursor[d], 1);
        int idx = row_start[d] + off;
        csr_src10[idx] = s * 10;  // pre-scaled float4 index
        csr_w[idx] = 0.9f * inv_out[s] * inv_in[d];  // (1-alpha) folded in
    }
}

// ---------------- one APPNP hop, pull-based, unroll-4 for MLP ----------------
__global__ __launch_bounds__(256) void hop_kernel(
    const float4* __restrict__ hcur, const float4* __restrict__ h0,
    const int* __restrict__ row_start,
    const int* __restrict__ csr_src10, const float* __restrict__ csr_w,
    float4* __restrict__ hnew)
{
    int gid = blockIdx.x * 256 + threadIdx.x;
    if (gid >= 10 * N_NODES) return;
    int d = gid / 10;
    int q = gid - d * 10;
    float4 hv0 = h0[gid];
    float4 acc = make_float4(0.1f * hv0.x, 0.1f * hv0.y, 0.1f * hv0.z, 0.1f * hv0.w);
    int j   = row_start[d];
    int end = row_start[d + 1];
    for (; j + 4 <= end; j += 4) {
        int s0 = csr_src10[j], s1 = csr_src10[j + 1];
        int s2 = csr_src10[j + 2], s3 = csr_src10[j + 3];
        float w0 = csr_w[j], w1 = csr_w[j + 1], w2 = csr_w[j + 2], w3 = csr_w[j + 3];
        float4 v0 = hcur[s0 + q];
        float4 v1 = hcur[s1 + q];
        float4 v2 = hcur[s2 + q];
        float4 v3 = hcur[s3 + q];
        acc.x = fmaf(w0, v0.x, acc.x); acc.y = fmaf(w0, v0.y, acc.y);
        acc.z = fmaf(w0, v0.z, acc.z); acc.w = fmaf(w0, v0.w, acc.w);
        acc.x = fmaf(w1, v1.x, acc.x); acc.y = fmaf(w1, v1.y, acc.y);
        acc.z = fmaf(w1, v1.z, acc.z); acc.w = fmaf(w1, v1.w, acc.w);
        acc.x = fmaf(w2, v2.x, acc.x); acc.y = fmaf(w2, v2.y, acc.y);
        acc.z = fmaf(w2, v2.z, acc.z); acc.w = fmaf(w2, v2.w, acc.w);
        acc.x = fmaf(w3, v3.x, acc.x); acc.y = fmaf(w3, v3.y, acc.y);
        acc.z = fmaf(w3, v3.z, acc.z); acc.w = fmaf(w3, v3.w, acc.w);
    }
    for (; j < end; ++j) {
        int s = csr_src10[j];
        float w = csr_w[j];
        float4 hv = hcur[s + q];
        acc.x = fmaf(w, hv.x, acc.x);
        acc.y = fmaf(w, hv.y, acc.y);
        acc.z = fmaf(w, hv.z, acc.z);
        acc.w = fmaf(w, hv.w, acc.w);
    }
    hnew[gid] = acc;
}

extern "C" void kernel_launch(void* const* d_in, const int* in_sizes, int n_in,
                              void* d_out, int out_size, void* d_ws, size_t ws_size,
                              hipStream_t stream) {
    const float* x  = (const float*)d_in[0];
    const int*   ei = (const int*)d_in[1];
    const int*   src = ei;
    const int*   dst = ei + N_EDGES;
    const float* Wb = (const float*)d_in[2];
    const float* bb = (const float*)d_in[3];
    const float* W1 = (const float*)d_in[4];
    const float* b1 = (const float*)d_in[5];
    const float* W2 = (const float*)d_in[6];
    const float* b2 = (const float*)d_in[7];

    float* out_adj    = (float*)d_out;
    float* out_scores = (float*)d_out + 4000000;

    float* h0      = (float*)d_ws;                  // 4,000,000 f
    float* hA      = h0 + 4000000;                  // 4,000,000 f
    int* deg_out   = (int*)(hA + 4000000);          // N
    int* deg_in    = deg_out + N_NODES;             // N
    int* cursor    = deg_in + N_NODES;              // N
    float* inv_out = (float*)(cursor + N_NODES);    // N
    float* inv_in  = inv_out + N_NODES;             // N
    int* row_start = (int*)(inv_in + N_NODES);      // N+1
    int* bsum      = row_start + N_NODES + 16;      // 1024
    int* csr_src10 = bsum + 1024;                   // E
    float* csr_w   = (float*)(csr_src10 + N_EDGES); // E
    short* WT      = (short*)(csr_w + N_EDGES);     // 48*512 bf16

    hipMemsetAsync(deg_out, 0, 3 * N_NODES * sizeof(int), stream);

    deg_kernel<<<N_EDGES / 256, 256, 0, stream>>>(src, dst, deg_out, deg_in);
    inv_kernel<<<NB1, 256, 0, stream>>>(deg_out, deg_in, inv_out, inv_in);
    scan1_kernel<<<NB1, 256, 0, stream>>>(deg_in, row_start, bsum);
    scan2_kernel<<<1, 512, 0, stream>>>(bsum);
    scan3_kernel<<<NB1, 256, 0, stream>>>(row_start, bsum);
    place_kernel<<<N_EDGES / 256, 256, 0, stream>>>(src, dst, inv_out, inv_in,
                                                    row_start, cursor, csr_src10, csr_w);

    wt_kernel<<<96, 256, 0, stream>>>(Wb, WT);
    scores_kernel<<<1563, 256, 0, stream>>>(
        x, (const short8*)WT, bb, out_scores);
    mlp_kernel<<<N_NODES / 4, 256, 0, stream>>>(out_scores, W1, b1, W2, b2, h0);

    const float* cur = h0;
    for (int k = 0; k < 10; ++k) {
        float* dstbuf = (k & 1) ? out_adj : hA;
        if (k == 9) dstbuf = out_adj;
        hop_kernel<<<(10 * N_NODES + 255) / 256, 256, 0, stream>>>(
            (const float4*)cur, (const float4*)h0, row_start,
            csr_src10, csr_w, (float4*)dstbuf);
        cur = dstbuf;
    }
}

// Round 4
// 1103.623 us; speedup vs baseline: 1.3965x; 1.0937x over previous
//
#include <hip/hip_runtime.h>

#define N_NODES 100000
#define N_EDGES 1600000
#define NB1 391  // ceil(N_NODES/256)

typedef __attribute__((ext_vector_type(8))) short short8;
typedef __attribute__((ext_vector_type(4))) float floatx4;

__device__ inline short bf16_rne(float f) {
    union { float f; unsigned u; } v; v.f = f;
    unsigned r = v.u + 0x7FFF + ((v.u >> 16) & 1);
    return (short)(r >> 16);
}

// ---------------- weight prep: all transposed, bf16, zero-padded ----------------
// WT  [48][512]: WT[m][k]  = W_base[k][m]
// W1T [64][64] : W1T[m][k] = W1[k][m] (k<40)
// W2T [48][64] : W2T[m][k] = W2[k][m] (m<40)
__global__ __launch_bounds__(256) void wt_kernel(
    const float* __restrict__ Wb, const float* __restrict__ W1,
    const float* __restrict__ W2,
    short* __restrict__ WT, short* __restrict__ W1T, short* __restrict__ W2T)
{
    int i = blockIdx.x * 256 + threadIdx.x;
    if (i < 48 * 512) {
        int m = i >> 9, k = i & 511;
        WT[i] = bf16_rne((m < 40 && k < 500) ? Wb[k * 40 + m] : 0.f);
    }
    if (i < 64 * 64) {
        int m = i >> 6, k = i & 63;
        W1T[i] = bf16_rne((k < 40) ? W1[k * 64 + m] : 0.f);
    }
    if (i < 48 * 64) {
        int m = i >> 6, k = i & 63;
        W2T[i] = bf16_rne((m < 40) ? W2[k * 40 + m] : 0.f);
    }
}

// ---------------- scores = x @ W_base + b_base via MFMA ----------------
__global__ __launch_bounds__(256) void scores_kernel(
    const float* __restrict__ x, const short8* __restrict__ WT8,
    const float* __restrict__ bb, float* __restrict__ scores)
{
    int wave = threadIdx.x >> 6;
    int lane = threadIdx.x & 63;
    int n0 = (blockIdx.x * 4 + wave) * 16;
    if (n0 >= N_NODES) return;
    int n = n0 + (lane & 15);
    int quad = lane >> 4;
    int m = lane & 15;
    const float* xrow = x + (size_t)n * 500 + quad * 8;

    floatx4 acc0 = {0,0,0,0}, acc1 = {0,0,0,0}, acc2 = {0,0,0,0};

    #pragma unroll 5
    for (int ks = 0; ks < 15; ++ks) {
        int k0 = ks * 32;
        float4 xa = *(const float4*)(xrow + k0);
        float4 xb = *(const float4*)(xrow + k0 + 4);
        short8 bf;
        bf[0] = bf16_rne(xa.x); bf[1] = bf16_rne(xa.y);
        bf[2] = bf16_rne(xa.z); bf[3] = bf16_rne(xa.w);
        bf[4] = bf16_rne(xb.x); bf[5] = bf16_rne(xb.y);
        bf[6] = bf16_rne(xb.z); bf[7] = bf16_rne(xb.w);
        int widx = (k0 >> 3) + quad;
        short8 a0 = WT8[(size_t)(0  + m) * 64 + widx];
        short8 a1 = WT8[(size_t)(16 + m) * 64 + widx];
        short8 a2 = WT8[(size_t)(32 + m) * 64 + widx];
        acc0 = __builtin_amdgcn_mfma_f32_16x16x32_bf16(a0, bf, acc0, 0, 0, 0);
        acc1 = __builtin_amdgcn_mfma_f32_16x16x32_bf16(a1, bf, acc1, 0, 0, 0);
        acc2 = __builtin_amdgcn_mfma_f32_16x16x32_bf16(a2, bf, acc2, 0, 0, 0);
    }
    {   // K tail: k = 480+quad*8+j; A rows are zero for k>=500
        int kbase = 480 + quad * 8;
        float4 xa = {0,0,0,0}, xb = {0,0,0,0};
        if (kbase + 8 <= 500) { xa = *(const float4*)(xrow + 480); xb = *(const float4*)(xrow + 484); }
        else if (kbase < 500) { xa = *(const float4*)(xrow + 480); }
        short8 bf;
        bf[0] = bf16_rne(xa.x); bf[1] = bf16_rne(xa.y);
        bf[2] = bf16_rne(xa.z); bf[3] = bf16_rne(xa.w);
        bf[4] = bf16_rne(xb.x); bf[5] = bf16_rne(xb.y);
        bf[6] = bf16_rne(xb.z); bf[7] = bf16_rne(xb.w);
        int widx = 60 + quad;
        short8 a0 = WT8[(size_t)(0  + m) * 64 + widx];
        short8 a1 = WT8[(size_t)(16 + m) * 64 + widx];
        short8 a2 = WT8[(size_t)(32 + m) * 64 + widx];
        acc0 = __builtin_amdgcn_mfma_f32_16x16x32_bf16(a0, bf, acc0, 0, 0, 0);
        acc1 = __builtin_amdgcn_mfma_f32_16x16x32_bf16(a1, bf, acc1, 0, 0, 0);
        acc2 = __builtin_amdgcn_mfma_f32_16x16x32_bf16(a2, bf, acc2, 0, 0, 0);
    }

    float* srow = scores + (size_t)n * 40;
    int mb = quad * 4;
    float4 b4 = *(const float4*)(bb + mb);
    *(float4*)(srow + mb) = make_float4(acc0[0] + b4.x, acc0[1] + b4.y,
                                        acc0[2] + b4.z, acc0[3] + b4.w);
    mb = 16 + quad * 4;
    b4 = *(const float4*)(bb + mb);
    *(float4*)(srow + mb) = make_float4(acc1[0] + b4.x, acc1[1] + b4.y,
                                        acc1[2] + b4.z, acc1[3] + b4.w);
    mb = 32 + quad * 4;
    if (mb < 40) {
        b4 = *(const float4*)(bb + mb);
        *(float4*)(srow + mb) = make_float4(acc2[0] + b4.x, acc2[1] + b4.y,
                                            acc2[2] + b4.z, acc2[3] + b4.w);
    }
}

// ---------------- fused softmax + MLP via MFMA ----------------
// One wave = 16 nodes. 5 waves/block (6250 waves = 1250 blocks exactly).
// B-frag layout throughout: B[k][n], n=lane&15 (node), k=quad*8+j.
// C-layout: D[m][n], n=lane&15 (node), m=quad*4+reg.
__global__ __launch_bounds__(320) void mlp_kernel(
    const float* __restrict__ scores,
    const short8* __restrict__ W1T8, const float* __restrict__ b1,
    const short8* __restrict__ W2T8, const float* __restrict__ b2,
    float* __restrict__ h0)
{
    __shared__ short hs[5][16 * 72];  // per-wave h1 tile, row stride 72 (16B align)
    int wave = threadIdx.x >> 6;
    int lane = threadIdx.x & 63;
    int q = lane >> 4;
    int n16 = lane & 15;
    int node = (blockIdx.x * 5 + wave) * 16 + n16;

    // ---- load scores in B-frag layout + softmax across quads ----
    const float* srow = scores + (size_t)node * 40;
    float4 xa = *(const float4*)(srow + q * 8);
    float4 xb = *(const float4*)(srow + q * 8 + 4);
    float4 xc = {0,0,0,0}, xd = {0,0,0,0};
    if (q == 0) { xc = *(const float4*)(srow + 32); xd = *(const float4*)(srow + 36); }

    float m = fmaxf(fmaxf(fmaxf(xa.x, xa.y), fmaxf(xa.z, xa.w)),
                    fmaxf(fmaxf(xb.x, xb.y), fmaxf(xb.z, xb.w)));
    if (q == 0)
        m = fmaxf(m, fmaxf(fmaxf(fmaxf(xc.x, xc.y), fmaxf(xc.z, xc.w)),
                           fmaxf(fmaxf(xd.x, xd.y), fmaxf(xd.z, xd.w))));
    m = fmaxf(m, __shfl_xor(m, 16));
    m = fmaxf(m, __shfl_xor(m, 32));

    float e0 = __expf(xa.x - m), e1 = __expf(xa.y - m), e2 = __expf(xa.z - m), e3 = __expf(xa.w - m);
    float e4 = __expf(xb.x - m), e5 = __expf(xb.y - m), e6 = __expf(xb.z - m), e7 = __expf(xb.w - m);
    float f0 = 0, f1 = 0, f2 = 0, f3 = 0, f4 = 0, f5 = 0, f6 = 0, f7 = 0;
    if (q == 0) {
        f0 = __expf(xc.x - m); f1 = __expf(xc.y - m); f2 = __expf(xc.z - m); f3 = __expf(xc.w - m);
        f4 = __expf(xd.x - m); f5 = __expf(xd.y - m); f6 = __expf(xd.z - m); f7 = __expf(xd.w - m);
    }
    float sum = e0 + e1 + e2 + e3 + e4 + e5 + e6 + e7 + f0 + f1 + f2 + f3 + f4 + f5 + f6 + f7;
    sum += __shfl_xor(sum, 16);
    sum += __shfl_xor(sum, 32);
    float inv = 1.f / sum;

    short8 bf_a, bf_b;
    bf_a[0] = bf16_rne(e0 * inv); bf_a[1] = bf16_rne(e1 * inv);
    bf_a[2] = bf16_rne(e2 * inv); bf_a[3] = bf16_rne(e3 * inv);
    bf_a[4] = bf16_rne(e4 * inv); bf_a[5] = bf16_rne(e5 * inv);
    bf_a[6] = bf16_rne(e6 * inv); bf_a[7] = bf16_rne(e7 * inv);
    bf_b[0] = bf16_rne(f0 * inv); bf_b[1] = bf16_rne(f1 * inv);
    bf_b[2] = bf16_rne(f2 * inv); bf_b[3] = bf16_rne(f3 * inv);
    bf_b[4] = bf16_rne(f4 * inv); bf_b[5] = bf16_rne(f5 * inv);
    bf_b[6] = bf16_rne(f6 * inv); bf_b[7] = bf16_rne(f7 * inv);

    // ---- h1 = relu(p @ W1 + b1): 4 m-tiles x 2 k-steps ----
    short* hw = &hs[wave][0];
    #pragma unroll
    for (int t = 0; t < 4; ++t) {
        floatx4 acc = {0, 0, 0, 0};
        short8 A0 = W1T8[(t * 16 + n16) * 8 + q];
        short8 A1 = W1T8[(t * 16 + n16) * 8 + 4 + q];
        acc = __builtin_amdgcn_mfma_f32_16x16x32_bf16(A0, bf_a, acc, 0, 0, 0);
        acc = __builtin_amdgcn_mfma_f32_16x16x32_bf16(A1, bf_b, acc, 0, 0, 0);
        float4 bv = *(const float4*)(b1 + t * 16 + q * 4);
        short4 pk;
        pk.x = bf16_rne(fmaxf(acc[0] + bv.x, 0.f));
        pk.y = bf16_rne(fmaxf(acc[1] + bv.y, 0.f));
        pk.z = bf16_rne(fmaxf(acc[2] + bv.z, 0.f));
        pk.w = bf16_rne(fmaxf(acc[3] + bv.w, 0.f));
        *(short4*)(hw + n16 * 72 + t * 16 + q * 4) = pk;  // C-layout: [node][col]
    }
    __syncthreads();

    // ---- re-read h1 in B-frag layout ----
    short8 h1a = *(const short8*)(hw + n16 * 72 + q * 8);
    short8 h1b = *(const short8*)(hw + n16 * 72 + 32 + q * 8);

    // ---- h2 = h1 @ W2 + b2: 3 m-tiles x 2 k-steps ----
    float* orow = h0 + (size_t)node * 40;
    #pragma unroll
    for (int t = 0; t < 3; ++t) {
        floatx4 acc = {0, 0, 0, 0};
        short8 A0 = W2T8[(t * 16 + n16) * 8 + q];
        short8 A1 = W2T8[(t * 16 + n16) * 8 + 4 + q];
        acc = __builtin_amdgcn_mfma_f32_16x16x32_bf16(A0, h1a, acc, 0, 0, 0);
        acc = __builtin_amdgcn_mfma_f32_16x16x32_bf16(A1, h1b, acc, 0, 0, 0);
        int mc = t * 16 + q * 4;
        if (mc < 40) {
            float4 bv = *(const float4*)(b2 + mc);
            *(float4*)(orow + mc) = make_float4(acc[0] + bv.x, acc[1] + bv.y,
                                                acc[2] + bv.z, acc[3] + bv.w);
        }
    }
}

// ---------------- degree count ----------------
__global__ __launch_bounds__(256) void deg_kernel(
    const int* __restrict__ src, const int* __restrict__ dst,
    int* __restrict__ deg_out, int* __restrict__ deg_in)
{
    int e = blockIdx.x * 256 + threadIdx.x;
    if (e < N_EDGES) {
        atomicAdd(&deg_out[src[e]], 1);
        atomicAdd(&deg_in[dst[e]], 1);
    }
}

__global__ __launch_bounds__(256) void inv_kernel(
    const int* __restrict__ deg_out, const int* __restrict__ deg_in,
    float* __restrict__ inv_out, float* __restrict__ inv_in)
{
    int i = blockIdx.x * 256 + threadIdx.x;
    if (i < N_NODES) {
        int a = deg_out[i], b = deg_in[i];
        inv_out[i] = (a > 0) ? rsqrtf((float)a) : 0.f;
        inv_in[i]  = (b > 0) ? rsqrtf((float)b) : 0.f;
    }
}

// ---------------- exclusive scan of deg_in -> row_start ----------------
__global__ __launch_bounds__(256) void scan1_kernel(
    const int* __restrict__ deg_in, int* __restrict__ row_start, int* __restrict__ bsum)
{
    __shared__ int tmp[256];
    int t = threadIdx.x;
    int i = blockIdx.x * 256 + t;
    int v = (i < N_NODES) ? deg_in[i] : 0;
    tmp[t] = v;
    __syncthreads();
    #pragma unroll
    for (int off = 1; off < 256; off <<= 1) {
        int add = (t >= off) ? tmp[t - off] : 0;
        __syncthreads();
        tmp[t] += add;
        __syncthreads();
    }
    if (i < N_NODES) row_start[i] = tmp[t] - v;
    if (t == 255) bsum[blockIdx.x] = tmp[t];
}

__global__ __launch_bounds__(512) void scan2_kernel(int* __restrict__ bsum)
{
    __shared__ int tmp[512];
    int t = threadIdx.x;
    int v = (t < NB1) ? bsum[t] : 0;
    tmp[t] = v;
    __syncthreads();
    #pragma unroll
    for (int off = 1; off < 512; off <<= 1) {
        int add = (t >= off) ? tmp[t - off] : 0;
        __syncthreads();
        tmp[t] += add;
        __syncthreads();
    }
    if (t < NB1) bsum[t] = tmp[t] - v;  // exclusive
}

__global__ __launch_bounds__(256) void scan3_kernel(
    int* __restrict__ row_start, const int* __restrict__ bsum)
{
    int i = blockIdx.x * 256 + threadIdx.x;
    if (i < N_NODES) row_start[i] += bsum[i >> 8];
    if (i == 0) row_start[N_NODES] = N_EDGES;  // sentinel
}

// ---------------- CSR placement + per-edge weight ----------------
__global__ __launch_bounds__(256) void place_kernel(
    const int* __restrict__ src, const int* __restrict__ dst,
    const float* __restrict__ inv_out, const float* __restrict__ inv_in,
    const int* __restrict__ row_start, int* __restrict__ cursor,
    int* __restrict__ csr_src10, float* __restrict__ csr_w)
{
    int e = blockIdx.x * 256 + threadIdx.x;
    if (e < N_EDGES) {
        int s = src[e], d = dst[e];
        int off = atomicAdd(&cursor[d], 1);
        int idx = row_start[d] + off;
        csr_src10[idx] = s * 10;  // pre-scaled float4 index
        csr_w[idx] = 0.9f * inv_out[s] * inv_in[d];  // (1-alpha) folded in
    }
}

// ---------------- one APPNP hop, pull-based, unroll-4 ----------------
__global__ __launch_bounds__(256) void hop_kernel(
    const float4* __restrict__ hcur, const float4* __restrict__ h0,
    const int* __restrict__ row_start,
    const int* __restrict__ csr_src10, const float* __restrict__ csr_w,
    float4* __restrict__ hnew)
{
    int gid = blockIdx.x * 256 + threadIdx.x;
    if (gid >= 10 * N_NODES) return;
    int d = gid / 10;
    int q = gid - d * 10;
    float4 hv0 = h0[gid];
    float4 acc = make_float4(0.1f * hv0.x, 0.1f * hv0.y, 0.1f * hv0.z, 0.1f * hv0.w);
    int j   = row_start[d];
    int end = row_start[d + 1];
    for (; j + 4 <= end; j += 4) {
        int s0 = csr_src10[j], s1 = csr_src10[j + 1];
        int s2 = csr_src10[j + 2], s3 = csr_src10[j + 3];
        float w0 = csr_w[j], w1 = csr_w[j + 1], w2 = csr_w[j + 2], w3 = csr_w[j + 3];
        float4 v0 = hcur[s0 + q];
        float4 v1 = hcur[s1 + q];
        float4 v2 = hcur[s2 + q];
        float4 v3 = hcur[s3 + q];
        acc.x = fmaf(w0, v0.x, acc.x); acc.y = fmaf(w0, v0.y, acc.y);
        acc.z = fmaf(w0, v0.z, acc.z); acc.w = fmaf(w0, v0.w, acc.w);
        acc.x = fmaf(w1, v1.x, acc.x); acc.y = fmaf(w1, v1.y, acc.y);
        acc.z = fmaf(w1, v1.z, acc.z); acc.w = fmaf(w1, v1.w, acc.w);
        acc.x = fmaf(w2, v2.x, acc.x); acc.y = fmaf(w2, v2.y, acc.y);
        acc.z = fmaf(w2, v2.z, acc.z); acc.w = fmaf(w2, v2.w, acc.w);
        acc.x = fmaf(w3, v3.x, acc.x); acc.y = fmaf(w3, v3.y, acc.y);
        acc.z = fmaf(w3, v3.z, acc.z); acc.w = fmaf(w3, v3.w, acc.w);
    }
    for (; j < end; ++j) {
        int s = csr_src10[j];
        float w = csr_w[j];
        float4 hv = hcur[s + q];
        acc.x = fmaf(w, hv.x, acc.x);
        acc.y = fmaf(w, hv.y, acc.y);
        acc.z = fmaf(w, hv.z, acc.z);
        acc.w = fmaf(w, hv.w, acc.w);
    }
    hnew[gid] = acc;
}

extern "C" void kernel_launch(void* const* d_in, const int* in_sizes, int n_in,
                              void* d_out, int out_size, void* d_ws, size_t ws_size,
                              hipStream_t stream) {
    const float* x  = (const float*)d_in[0];
    const int*   ei = (const int*)d_in[1];
    const int*   src = ei;
    const int*   dst = ei + N_EDGES;
    const float* Wb = (const float*)d_in[2];
    const float* bb = (const float*)d_in[3];
    const float* W1 = (const float*)d_in[4];
    const float* b1 = (const float*)d_in[5];
    const float* W2 = (const float*)d_in[6];
    const float* b2 = (const float*)d_in[7];

    float* out_adj    = (float*)d_out;
    float* out_scores = (float*)d_out + 4000000;

    float* h0      = (float*)d_ws;                  // 4,000,000 f
    float* hA      = h0 + 4000000;                  // 4,000,000 f
    int* deg_out   = (int*)(hA + 4000000);          // N
    int* deg_in    = deg_out + N_NODES;             // N
    int* cursor    = deg_in + N_NODES;              // N
    float* inv_out = (float*)(cursor + N_NODES);    // N
    float* inv_in  = inv_out + N_NODES;             // N
    int* row_start = (int*)(inv_in + N_NODES);      // N+1
    int* bsum      = row_start + N_NODES + 16;      // 1024
    int* csr_src10 = bsum + 1024;                   // E
    float* csr_w   = (float*)(csr_src10 + N_EDGES); // E
    short* WT      = (short*)(csr_w + N_EDGES);     // 48*512 bf16
    short* W1T     = WT + 48 * 512;                 // 64*64 bf16
    short* W2T     = W1T + 64 * 64;                 // 48*64 bf16

    hipMemsetAsync(deg_out, 0, 3 * N_NODES * sizeof(int), stream);

    deg_kernel<<<N_EDGES / 256, 256, 0, stream>>>(src, dst, deg_out, deg_in);
    inv_kernel<<<NB1, 256, 0, stream>>>(deg_out, deg_in, inv_out, inv_in);
    scan1_kernel<<<NB1, 256, 0, stream>>>(deg_in, row_start, bsum);
    scan2_kernel<<<1, 512, 0, stream>>>(bsum);
    scan3_kernel<<<NB1, 256, 0, stream>>>(row_start, bsum);
    place_kernel<<<N_EDGES / 256, 256, 0, stream>>>(src, dst, inv_out, inv_in,
                                                    row_start, cursor, csr_src10, csr_w);

    wt_kernel<<<96, 256, 0, stream>>>(Wb, W1, W2, WT, W1T, W2T);
    scores_kernel<<<1563, 256, 0, stream>>>(
        x, (const short8*)WT, bb, out_scores);
    mlp_kernel<<<1250, 320, 0, stream>>>(
        out_scores, (const short8*)W1T, b1, (const short8*)W2T, b2, h0);

    const float* cur = h0;
    for (int k = 0; k < 10; ++k) {
        float* dstbuf = (k & 1) ? out_adj : hA;
        if (k == 9) dstbuf = out_adj;
        hop_kernel<<<(10 * N_NODES + 255) / 256, 256, 0, stream>>>(
            (const float4*)cur, (const float4*)h0, row_start,
            csr_src10, csr_w, (float4*)dstbuf);
        cur = dstbuf;
    }
}